// Round 1
// baseline (123.255 us; speedup 1.0000x reference)
//
#include <hip/hip_runtime.h>

#define MTOT 8192
#define NTOT 8192
#define DD   64
#define PITCH 132   // fp32 elements; 132*4B=528B row stride: 16B-aligned, bank-shift 4/row

// 256 threads, 128x128 output tile, K=64 fully staged (no K loop over tiles).
__global__ __launch_bounds__(256, 2)
void rbf_tile_kernel(const float* __restrict__ X,
                     const float* __restrict__ Y,
                     const float* __restrict__ gamma_p,
                     float* __restrict__ out)
{
    __shared__ float Xs[DD][PITCH];   // transposed: Xs[k][m]
    __shared__ float Ys[DD][PITCH];   // transposed: Ys[k][n]
    __shared__ float xq[128];
    __shared__ float yq[128];

    const int t  = threadIdx.x;
    const int bm = blockIdx.y, bn = blockIdx.x;
    const long row0 = (long)bm * 128;
    const long col0 = (long)bn * 128;

    // ---- stage both tiles, transposing into LDS ----
    // mapping: c4 = (t&3)|((i&3)<<2), r = (t>>2)|((i>>2)<<6)
    // global: 16 consecutive rows x 4 consecutive float4 per instr (64B granules, coalesced)
    // LDS write bank = 16*(t&1) + (t>>2) + const -> 32 banks, 2-way (free)
    #pragma unroll
    for (int i = 0; i < 8; ++i) {
        const int c4 = (t & 3) | ((i & 3) << 2);
        const int r  = (t >> 2) | ((i >> 2) << 6);
        const float4 vx = *reinterpret_cast<const float4*>(X + (row0 + r) * DD + c4 * 4);
        const float4 vy = *reinterpret_cast<const float4*>(Y + (col0 + r) * DD + c4 * 4);
        const int c = c4 * 4;
        Xs[c + 0][r] = vx.x; Xs[c + 1][r] = vx.y; Xs[c + 2][r] = vx.z; Xs[c + 3][r] = vx.w;
        Ys[c + 0][r] = vy.x; Ys[c + 1][r] = vy.y; Ys[c + 2][r] = vy.z; Ys[c + 3][r] = vy.w;
    }
    __syncthreads();

    // ---- row norms from staged tiles (threads 0..127 -> X, 128..255 -> Y) ----
    {
        const int r = t & 127;
        float s0 = 0.f, s1 = 0.f, s2 = 0.f, s3 = 0.f;
        if (t < 128) {
            #pragma unroll
            for (int k = 0; k < DD; k += 4) {
                const float v0 = Xs[k + 0][r], v1 = Xs[k + 1][r];
                const float v2 = Xs[k + 2][r], v3 = Xs[k + 3][r];
                s0 = fmaf(v0, v0, s0); s1 = fmaf(v1, v1, s1);
                s2 = fmaf(v2, v2, s2); s3 = fmaf(v3, v3, s3);
            }
            xq[r] = (s0 + s1) + (s2 + s3);
        } else {
            #pragma unroll
            for (int k = 0; k < DD; k += 4) {
                const float v0 = Ys[k + 0][r], v1 = Ys[k + 1][r];
                const float v2 = Ys[k + 2][r], v3 = Ys[k + 3][r];
                s0 = fmaf(v0, v0, s0); s1 = fmaf(v1, v1, s1);
                s2 = fmaf(v2, v2, s2); s3 = fmaf(v3, v3, s3);
            }
            yq[r] = (s0 + s1) + (s2 + s3);
        }
    }
    __syncthreads();

    // ---- main accumulation: 8x8 per thread, split into two 4-row/4-col halves ----
    const int tx = t & 15;        // col group 0..15
    const int ty = t >> 4;        // row group 0..15  (within a wave ty spans 0..3)
    float acc[8][8];
    #pragma unroll
    for (int i = 0; i < 8; ++i)
        #pragma unroll
        for (int j = 0; j < 8; ++j) acc[i][j] = 0.f;

    #pragma unroll 8
    for (int k = 0; k < DD; ++k) {
        float a[8], b[8];
        *reinterpret_cast<float4*>(&a[0]) = *reinterpret_cast<const float4*>(&Xs[k][ty * 4]);
        *reinterpret_cast<float4*>(&a[4]) = *reinterpret_cast<const float4*>(&Xs[k][64 + ty * 4]);
        *reinterpret_cast<float4*>(&b[0]) = *reinterpret_cast<const float4*>(&Ys[k][tx * 4]);
        *reinterpret_cast<float4*>(&b[4]) = *reinterpret_cast<const float4*>(&Ys[k][64 + tx * 4]);
        #pragma unroll
        for (int i = 0; i < 8; ++i)
            #pragma unroll
            for (int j = 0; j < 8; ++j)
                acc[i][j] = fmaf(a[i], b[j], acc[i][j]);
    }

    // ---- epilogue: s = xq + yq - 2*acc; out = exp(-g * max(s,0)) ----
    const float g = gamma_p[0];
    float xr[8], yr[8];
    #pragma unroll
    for (int i = 0; i < 8; ++i) xr[i] = xq[(i & 4) * 16 + ty * 4 + (i & 3)];
    #pragma unroll
    for (int j = 0; j < 8; ++j) yr[j] = yq[(j & 4) * 16 + tx * 4 + (j & 3)];

    #pragma unroll
    for (int i = 0; i < 8; ++i) {
        const long orow = row0 + (i & 4) * 16 + ty * 4 + (i & 3);
        float e[8];
        #pragma unroll
        for (int j = 0; j < 8; ++j) {
            float s = fmaf(-2.f, acc[i][j], xr[i] + yr[j]);
            s = fmaxf(s, 0.f);
            e[j] = __expf(-g * s);
        }
        float* op0 = out + orow * NTOT + col0 + tx * 4;
        float* op1 = out + orow * NTOT + col0 + 64 + tx * 4;
        *reinterpret_cast<float4*>(op0) = make_float4(e[0], e[1], e[2], e[3]);
        *reinterpret_cast<float4*>(op1) = make_float4(e[4], e[5], e[6], e[7]);
    }
}

extern "C" void kernel_launch(void* const* d_in, const int* in_sizes, int n_in,
                              void* d_out, int out_size, void* d_ws, size_t ws_size,
                              hipStream_t stream) {
    (void)in_sizes; (void)n_in; (void)d_ws; (void)ws_size; (void)out_size;
    const float* X = (const float*)d_in[0];
    const float* Y = (const float*)d_in[1];
    const float* gamma_p = (const float*)d_in[2];
    float* out = (float*)d_out;

    dim3 grid(NTOT / 128, MTOT / 128);  // (64, 64)
    dim3 block(256);
    rbf_tile_kernel<<<grid, block, 0, stream>>>(X, Y, gamma_p, out);
}

// Round 2
// 80.691 us; speedup vs baseline: 1.5275x; 1.5275x over previous
//
#include <hip/hip_runtime.h>

#define MTOT 8192
#define NTOT 8192
#define DD   64

typedef __bf16 bf16x8 __attribute__((ext_vector_type(8)));
typedef float  f32x16 __attribute__((ext_vector_type(16)));
typedef unsigned short u16x4 __attribute__((ext_vector_type(4)));

// Round-to-nearest-even fp32 -> bf16 (top 16 bits), bit-trick (no __bf16 scalar ops).
__device__ __forceinline__ unsigned short bf16_rne(float v) {
    unsigned int u = __float_as_uint(v);
    u = u + 0x7FFFu + ((u >> 16) & 1u);
    return (unsigned short)(u >> 16);
}
__device__ __forceinline__ float bf16_to_f32(unsigned short h) {
    return __uint_as_float(((unsigned int)h) << 16);
}

#define MFMA(a, b, c) __builtin_amdgcn_mfma_f32_32x32x16_bf16((a), (b), (c), 0, 0, 0)

// 256 threads (4 waves), 128x128 output tile. Split-bf16 MFMA: hh + hl + lh.
__global__ __launch_bounds__(256, 2)
void rbf_mfma_kernel(const float* __restrict__ X,
                     const float* __restrict__ Y,
                     const float* __restrict__ gamma_p,
                     float* __restrict__ out)
{
    // Fragment-linear LDS: [tile(32 rows)][kstep(16 k)][lane][slot(8 bf16)]
    // lane = (row&31) | ((k>>3)&1)<<5 ; slot = k&7. ds_read_b128 is lane-linear.
    __shared__ unsigned short XfH[4][4][64][8];
    __shared__ unsigned short XfL[4][4][64][8];
    __shared__ unsigned short YfH[4][4][64][8];
    __shared__ unsigned short YfL[4][4][64][8];
    __shared__ float xq[128];
    __shared__ float yq[128];

    const int t = threadIdx.x;
    const long row0 = (long)blockIdx.y * 128;
    const long col0 = (long)blockIdx.x * 128;

    // ---- stage + split fp32 -> (hi, lo) bf16 into fragment layout ----
    {
        const int k0   = (t & 15) * 4;          // k base, multiple of 4
        const int ks   = k0 >> 4;               // k-step 0..3
        const int l32  = ((k0 >> 3) & 1) << 5;  // k-half -> lane bit 5
        const int slot = k0 & 4;                // 0 or 4
        #pragma unroll
        for (int i = 0; i < 8; ++i) {
            const int row  = (t >> 4) + i * 16;
            const int mt   = row >> 5;
            const int lane = (row & 31) | l32;
            const float4 vx = *reinterpret_cast<const float4*>(X + (row0 + row) * DD + k0);
            const float4 vy = *reinterpret_cast<const float4*>(Y + (col0 + row) * DD + k0);
            float xv[4] = {vx.x, vx.y, vx.z, vx.w};
            float yv[4] = {vy.x, vy.y, vy.z, vy.w};
            u16x4 xh, xl, yh, yl;
            #pragma unroll
            for (int e = 0; e < 4; ++e) {
                const unsigned short hx = bf16_rne(xv[e]);
                xh[e] = hx;
                xl[e] = bf16_rne(xv[e] - bf16_to_f32(hx));
                const unsigned short hy = bf16_rne(yv[e]);
                yh[e] = hy;
                yl[e] = bf16_rne(yv[e] - bf16_to_f32(hy));
            }
            *reinterpret_cast<u16x4*>(&XfH[mt][ks][lane][slot]) = xh;
            *reinterpret_cast<u16x4*>(&XfL[mt][ks][lane][slot]) = xl;
            *reinterpret_cast<u16x4*>(&YfH[mt][ks][lane][slot]) = yh;
            *reinterpret_cast<u16x4*>(&YfL[mt][ks][lane][slot]) = yl;
        }
    }

    // ---- row norms in fp32 from global (L1/L2-hot: just read by staging) ----
    {
        const int r = t & 127;
        const float* p = (t < 128) ? (X + (row0 + r) * DD) : (Y + (col0 + r) * DD);
        float s0 = 0.f, s1 = 0.f, s2 = 0.f, s3 = 0.f;
        #pragma unroll
        for (int c = 0; c < 16; ++c) {
            const float4 v = reinterpret_cast<const float4*>(p)[c];
            s0 = fmaf(v.x, v.x, s0); s1 = fmaf(v.y, v.y, s1);
            s2 = fmaf(v.z, v.z, s2); s3 = fmaf(v.w, v.w, s3);
        }
        const float s = (s0 + s1) + (s2 + s3);
        if (t < 128) xq[r] = s; else yq[r] = s;
    }
    __syncthreads();

    // ---- per-wave 64x64 quadrant: 2x2 tiles of 32x32, K=64 in 4 steps ----
    const int w = t >> 6;
    const int l = t & 63;
    const int mt0 = (w >> 1) * 2;
    const int nt0 = (w & 1) * 2;

    bf16x8 aH[2][4], aL[2][4];
    #pragma unroll
    for (int i = 0; i < 2; ++i)
        #pragma unroll
        for (int ks = 0; ks < 4; ++ks) {
            aH[i][ks] = *reinterpret_cast<const bf16x8*>(&XfH[mt0 + i][ks][l][0]);
            aL[i][ks] = *reinterpret_cast<const bf16x8*>(&XfL[mt0 + i][ks][l][0]);
        }

    f32x16 acc[2][2];
    #pragma unroll
    for (int i = 0; i < 2; ++i)
        #pragma unroll
        for (int j = 0; j < 2; ++j)
            #pragma unroll
            for (int r = 0; r < 16; ++r) acc[i][j][r] = 0.f;

    #pragma unroll
    for (int ks = 0; ks < 4; ++ks) {
        const bf16x8 b0h = *reinterpret_cast<const bf16x8*>(&YfH[nt0 + 0][ks][l][0]);
        const bf16x8 b1h = *reinterpret_cast<const bf16x8*>(&YfH[nt0 + 1][ks][l][0]);
        const bf16x8 b0l = *reinterpret_cast<const bf16x8*>(&YfL[nt0 + 0][ks][l][0]);
        const bf16x8 b1l = *reinterpret_cast<const bf16x8*>(&YfL[nt0 + 1][ks][l][0]);
        acc[0][0] = MFMA(aH[0][ks], b0h, acc[0][0]);
        acc[0][1] = MFMA(aH[0][ks], b1h, acc[0][1]);
        acc[1][0] = MFMA(aH[1][ks], b0h, acc[1][0]);
        acc[1][1] = MFMA(aH[1][ks], b1h, acc[1][1]);
        acc[0][0] = MFMA(aH[0][ks], b0l, acc[0][0]);
        acc[0][1] = MFMA(aH[0][ks], b1l, acc[0][1]);
        acc[1][0] = MFMA(aH[1][ks], b0l, acc[1][0]);
        acc[1][1] = MFMA(aH[1][ks], b1l, acc[1][1]);
        acc[0][0] = MFMA(aL[0][ks], b0h, acc[0][0]);
        acc[0][1] = MFMA(aL[0][ks], b1h, acc[0][1]);
        acc[1][0] = MFMA(aL[1][ks], b0h, acc[1][0]);
        acc[1][1] = MFMA(aL[1][ks], b1h, acc[1][1]);
    }

    // ---- epilogue: s = xq + yq - 2*dot ; out = exp(-g * max(s,0)) ----
    // C/D layout (HW-verified): col = lane&31, row = (reg&3) + 8*(reg>>2) + 4*(lane>>5)
    const float g = gamma_p[0];
    const int l5x4 = (l >> 5) * 4;
    const int ln = l & 31;
    #pragma unroll
    for (int i = 0; i < 2; ++i) {
        const int mt = mt0 + i;
        float xv[16];
        #pragma unroll
        for (int r = 0; r < 16; ++r)
            xv[r] = xq[mt * 32 + (r & 3) + 8 * (r >> 2) + l5x4];
        #pragma unroll
        for (int j = 0; j < 2; ++j) {
            const int nt = nt0 + j;
            const float yv = yq[nt * 32 + ln];
            const long gr = row0 + mt * 32;
            const long gc = col0 + nt * 32 + ln;
            #pragma unroll
            for (int r = 0; r < 16; ++r) {
                float s = fmaf(-2.f, acc[i][j][r], xv[r] + yv);
                s = fmaxf(s, 0.f);
                const long rr = gr + (r & 3) + 8 * (r >> 2) + l5x4;
                out[rr * NTOT + gc] = __expf(-g * s);
            }
        }
    }
}

extern "C" void kernel_launch(void* const* d_in, const int* in_sizes, int n_in,
                              void* d_out, int out_size, void* d_ws, size_t ws_size,
                              hipStream_t stream) {
    (void)in_sizes; (void)n_in; (void)d_ws; (void)ws_size; (void)out_size;
    const float* X = (const float*)d_in[0];
    const float* Y = (const float*)d_in[1];
    const float* gamma_p = (const float*)d_in[2];
    float* out = (float*)d_out;

    dim3 grid(NTOT / 128, MTOT / 128);  // (64, 64)
    dim3 block(256);
    rbf_mfma_kernel<<<grid, block, 0, stream>>>(X, Y, gamma_p, out);
}